// Round 3
// baseline (121.914 us; speedup 1.0000x reference)
//
#include <hip/hip_runtime.h>
#include <hip/hip_bf16.h>
#include <math.h>

#define NN 4096
#define BB 4
// (1/64) * log2(e)  -- folds 1/sqrt(N) and exp->exp2 conversion
#define SCL 0.022542110013890054f
#define LOG2E 1.4426950408889634f

typedef __attribute__((ext_vector_type(8))) short bf16x8;
typedef __attribute__((ext_vector_type(4))) float f32x4;

__device__ __forceinline__ float exp2_fast(float x) {
  float r; asm("v_exp_f32 %0, %1" : "=v"(r) : "v"(x)); return r;
}

// ---------------------------------------------------------------------------
// Kernel 1 (fused by block range):
//   blocks [0,2048):    Wh = h@W -> WhT bf16 [B][64][4096]; Wh1s/Wh2s scaled.
//   blocks [2048,4096): adj int32 -> bitmask (1 bit per edge, 2 MB) via ballot.
// ---------------------------------------------------------------------------
__global__ __launch_bounds__(256)
void k_prep(const float* __restrict__ h, const float* __restrict__ W,
            const float* __restrict__ a, const int* __restrict__ adj,
            unsigned short* __restrict__ WhT, float* __restrict__ Wh1s,
            float* __restrict__ Wh2s, unsigned long long* __restrict__ bits) {
  const int t = threadIdx.x;
  const int bi = blockIdx.x;
  if (bi >= 2048) {
    // ---- adj -> bitmask: 2 rows per block, row-half per wave ----
    const int ci = bi - 2048;
    const int w = t >> 6, lane = t & 63;
    const int row = ci * 2 + (w >> 1);
    const int* __restrict__ arow = adj + (size_t)row * NN + (w & 1) * 2048;
    unsigned long long* __restrict__ brow = bits + row * 64 + (w & 1) * 32;
#pragma unroll 4
    for (int k = 0; k < 32; ++k) {
      unsigned long long m = __ballot(arow[k * 64 + lane] > 0);
      if (lane == 0) brow[k] = m;
    }
    return;
  }
  // ---- Wh path: 8 rows (same batch) per block ----
  __shared__ float sW[4096];
  __shared__ unsigned short T[64][8];
#pragma unroll
  for (int i = 0; i < 16; ++i) sW[i * 256 + t] = W[i * 256 + t];
  __syncthreads();
  const int wv = t >> 6, lane = t & 63;
  const float a1 = a[lane], a2 = a[64 + lane];
  const int row0 = bi * 8;
  for (int r = 0; r < 2; ++r) {
    const int row = row0 + wv * 2 + r;
    const float* hr = h + (size_t)row * 64;
    float acc = 0.f;
#pragma unroll
    for (int k = 0; k < 64; ++k) acc = fmaf(hr[k], sW[k * 64 + lane], acc);
    __hip_bfloat16 bv = __float2bfloat16(acc);
    T[lane][wv * 2 + r] = *(unsigned short*)&bv;
    float r1 = acc * a1, r2 = acc * a2;
#pragma unroll
    for (int sft = 32; sft; sft >>= 1) { r1 += __shfl_xor(r1, sft); r2 += __shfl_xor(r2, sft); }
    if (lane == 0) { Wh1s[row] = r1 * SCL; Wh2s[row] = r2 * SCL; }
  }
  __syncthreads();
  const int f = t >> 2, jp4 = t & 3;
  const int bidx = row0 >> 12, n0 = row0 & 4095;
  unsigned v = *(unsigned*)&T[f][jp4 * 2];
  *(unsigned*)(WhT + (((size_t)(bidx * 64 + f)) << 12) + n0 + jp4 * 2) = v;
}

// ---------------------------------------------------------------------------
// Kernel 2: fused masked-softmax attention (MFMA PV) + BN + residual + ELU.
// 1024 thr = 16 waves: wave (b = w>>2, s = w&3); block owns 16 node rows.
// Lane (jp = lane&15, rg = lane>>4) computes P[i=jp][k=rg*8+e] (e=0..7) in
// registers -- exactly the MFMA B-fragment layout. Main loop: no LDS, no
// barriers; adj mask read as 1 dword of bits per lane per iteration.
// ---------------------------------------------------------------------------
__global__ __launch_bounds__(1024)
void k_gat(const float* __restrict__ h, const unsigned* __restrict__ bits,
           const float* __restrict__ gamma, const float* __restrict__ beta,
           const unsigned short* __restrict__ WhT,
           const float* __restrict__ Wh1s, const float* __restrict__ Wh2s,
           float* __restrict__ out) {
  __shared__ float hp[4][4][16][68];   // h' partials [b][s][i][f] (+pad), ~70 KB
  __shared__ float ls2[4][4][16];      // denom partials [s][b][i]
  __shared__ float bn2[4][16][2];      // BN partials [b][i][{s1,s2}]

  const int t = threadIdx.x;
  const int w = t >> 6, lane = t & 63;
  const int b = w >> 2, s = w & 3;
  const int i0 = blockIdx.x * 16;
  const int jp = lane & 15;   // score row i / MFMA output col
  const int rg = lane >> 4;   // k-group

  const float w1 = Wh1s[b * NN + i0 + jp];
  const float* __restrict__ w2base = Wh2s + b * NN;
  const unsigned* __restrict__ bitrow = bits + (size_t)(i0 + jp) * 128 + s;
  const unsigned short* __restrict__ abase =
      WhT + (((size_t)(b * 64 + jp)) << 12) + rg * 8;   // A row f = ft*16+jp

  f32x4 acc[4];
#pragma unroll
  for (int ft = 0; ft < 4; ++ft) acc[ft] = (f32x4){0.f, 0.f, 0.f, 0.f};
  float lsum = 0.f;

  for (int jt = 0; jt < 32; ++jt) {
    const int j0 = jt * 128 + s * 32;          // this wave's 32-wide j window
    // long-latency-first: mask word + Wh2, then A-frags
    const unsigned word = bitrow[jt * 4];
    const int jj = j0 + rg * 8;
    const float4 w2a = *(const float4*)(w2base + jj);
    const float4 w2b = *(const float4*)(w2base + jj + 4);
    bf16x8 af[4];
#pragma unroll
    for (int ft = 0; ft < 4; ++ft)
      af[ft] = *(const bf16x8*)(abase + (ft << 16) + j0);

    const unsigned mb = word >> (rg * 8);
    const float wv[8] = {w2a.x, w2a.y, w2a.z, w2a.w, w2b.x, w2b.y, w2b.z, w2b.w};
    float p[8];
#pragma unroll
    for (int e = 0; e < 8; ++e) {
      float y = w1 + wv[e];
      float tt = fmaxf(y, 0.2f * y);           // LeakyReLU (scores pre-scaled)
      tt = ((mb >> e) & 1u) ? tt : -1e30f;     // mask -> exp2 underflows to 0
      float pv = exp2_fast(tt);
      lsum += pv;
      p[e] = pv;
    }
    bf16x8 bfr;
#pragma unroll
    for (int e = 0; e < 8; ++e) {
      __hip_bfloat16 bv = __float2bfloat16(p[e]);
      bfr[e] = *(short*)&bv;
    }
#pragma unroll
    for (int ft = 0; ft < 4; ++ft)
      acc[ft] = __builtin_amdgcn_mfma_f32_16x16x32_bf16(af[ft], bfr, acc[ft], 0, 0, 0);
  }

  // denom: lane holds row jp's partial over its 8 k's; reduce over rg lanes
  lsum += __shfl_xor(lsum, 16);
  lsum += __shfl_xor(lsum, 32);
  if (lane < 16) ls2[s][b][jp] = lsum;

  // stash h' partials (C-layout: acc[ft][r] = D[f=ft*16+rg*4+r][i=jp])
#pragma unroll
  for (int ft = 0; ft < 4; ++ft)
    *(f32x4*)&hp[b][s][jp][ft * 16 + rg * 4] = acc[ft];
  __syncthreads();

  if (s == 0) {
    const float ltot = ls2[0][b][jp] + ls2[1][b][jp] + ls2[2][b][jp] + ls2[3][b][jp];
    const float invl = 1.f / ltot;
    float vv[4][4];
    float s1 = 0.f, s2 = 0.f;
#pragma unroll
    for (int ft = 0; ft < 4; ++ft) {
      const int fo = ft * 16 + rg * 4;
      f32x4 x0 = *(f32x4*)&hp[b][0][jp][fo];
      f32x4 x1 = *(f32x4*)&hp[b][1][jp][fo];
      f32x4 x2 = *(f32x4*)&hp[b][2][jp][fo];
      f32x4 x3 = *(f32x4*)&hp[b][3][jp][fo];
#pragma unroll
      for (int r = 0; r < 4; ++r) {
        float x = (x0[r] + x1[r] + x2[r] + x3[r]) * invl;  // normalized h'[f][i=jp]
        vv[ft][r] = x;
        s1 += x; s2 += x * x;
      }
    }
    s1 += __shfl_xor(s1, 16); s1 += __shfl_xor(s1, 32);
    s2 += __shfl_xor(s2, 16); s2 += __shfl_xor(s2, 32);
    if (rg == 0) { bn2[b][jp][0] = s1; bn2[b][jp][1] = s2; }
    __syncthreads();
    const float t1 = bn2[0][jp][0] + bn2[1][jp][0] + bn2[2][jp][0] + bn2[3][jp][0];
    const float t2 = bn2[0][jp][1] + bn2[1][jp][1] + bn2[2][jp][1] + bn2[3][jp][1];
    const float mean = t1 * (1.f / 256.f);
    const float var  = t2 * (1.f / 256.f) - mean * mean;
    const float sc = gamma[i0 + jp] * rsqrtf(var + 1e-5f);
    const float bt = beta[i0 + jp];
    const float* hrow = h + ((size_t)(b * NN + i0 + jp)) * 64;
    float* orow = out + ((size_t)(b * NN + i0 + jp)) * 64;
#pragma unroll
    for (int ft = 0; ft < 4; ++ft) {
      const int fo = ft * 16 + rg * 4;
      float4 hv = *(const float4*)(hrow + fo);
      float o0 = sc * (vv[ft][0] - mean) + bt + hv.x;
      float o1 = sc * (vv[ft][1] - mean) + bt + hv.y;
      float o2 = sc * (vv[ft][2] - mean) + bt + hv.z;
      float o3 = sc * (vv[ft][3] - mean) + bt + hv.w;
      o0 = o0 > 0.f ? o0 : exp2_fast(o0 * LOG2E) - 1.f;
      o1 = o1 > 0.f ? o1 : exp2_fast(o1 * LOG2E) - 1.f;
      o2 = o2 > 0.f ? o2 : exp2_fast(o2 * LOG2E) - 1.f;
      o3 = o3 > 0.f ? o3 : exp2_fast(o3 * LOG2E) - 1.f;
      *(float4*)(orow + fo) = make_float4(o0, o1, o2, o3);
    }
  } else {
    __syncthreads();   // match the s==0 path's second barrier
  }
}

// ---------------------------------------------------------------------------
extern "C" void kernel_launch(void* const* d_in, const int* in_sizes, int n_in,
                              void* d_out, int out_size, void* d_ws, size_t ws_size,
                              hipStream_t stream) {
  (void)in_sizes; (void)n_in; (void)out_size; (void)ws_size;
  const float* h     = (const float*)d_in[0];
  const int*   adj   = (const int*)d_in[1];
  const float* W     = (const float*)d_in[2];
  const float* a     = (const float*)d_in[3];
  const float* gamma = (const float*)d_in[4];
  const float* beta  = (const float*)d_in[5];
  float* out = (float*)d_out;

  char* ws = (char*)d_ws;
  unsigned short* WhT = (unsigned short*)ws;                       // 2 MB
  float* Wh1s = (float*)(ws + (size_t)BB * 64 * NN * 2);           // 64 KB
  float* Wh2s = Wh1s + BB * NN;                                    // 64 KB
  unsigned long long* bits =
      (unsigned long long*)(ws + (size_t)BB * 64 * NN * 2 + 2 * BB * NN * 4); // 2 MB

  k_prep<<<4096, 256, 0, stream>>>(h, W, a, adj, WhT, Wh1s, Wh2s, bits);
  k_gat<<<NN / 16, 1024, 0, stream>>>(h, (const unsigned*)bits, gamma, beta,
                                      WhT, Wh1s, Wh2s, out);
}

// Round 4
// 81.009 us; speedup vs baseline: 1.5049x; 1.5049x over previous
//
#include <hip/hip_runtime.h>
#include <hip/hip_bf16.h>
#include <math.h>

#define NN 4096
#define BB 4
// (1/64) * log2(e)  -- folds 1/sqrt(N) and exp->exp2 conversion
#define SCL 0.022542110013890054f
#define LOG2E 1.4426950408889634f

typedef __attribute__((ext_vector_type(8))) short bf16x8;
typedef __attribute__((ext_vector_type(4))) float f32x4;

__device__ __forceinline__ float exp2_fast(float x) {
  float r; asm("v_exp_f32 %0, %1" : "=v"(r) : "v"(x)); return r;
}
__device__ __forceinline__ short bf16s(float x) {
  __hip_bfloat16 b = __float2bfloat16(x);
  return *(short*)&b;
}

// ---------------------------------------------------------------------------
// Kernel 1 (fused by block range):
//   blocks [0,2048):    Wh = h@W -> WhT bf16 [B][64][4096]; Wh1s/Wh2s scaled.
//   blocks [2048,4096): adj int32 -> bitmask. Per thread: 8 x int4 (128 B)
//   -> one u32 of LSBs (adj in {0,1}); coalesced loads AND stores, no ballot.
// ---------------------------------------------------------------------------
__global__ __launch_bounds__(256)
void k_prep(const float* __restrict__ h, const float* __restrict__ W,
            const float* __restrict__ a, const int* __restrict__ adj,
            unsigned short* __restrict__ WhT, float* __restrict__ Wh1s,
            float* __restrict__ Wh2s, unsigned* __restrict__ bits) {
  const int t = threadIdx.x;
  const int bi = blockIdx.x;
  if (bi >= 2048) {
    const int ti = (bi - 2048) * 256 + t;      // 0 .. 524287
    const int r = ti >> 7, g = ti & 127;       // row, 32-j word index
    const int4* __restrict__ ap = (const int4*)(adj + ((size_t)r << 12) + (g << 5));
    unsigned m = 0;
#pragma unroll
    for (int q = 0; q < 8; ++q) {
      int4 av = ap[q];
      m |= (unsigned)(av.x & 1) << (q * 4 + 0);
      m |= (unsigned)(av.y & 1) << (q * 4 + 1);
      m |= (unsigned)(av.z & 1) << (q * 4 + 2);
      m |= (unsigned)(av.w & 1) << (q * 4 + 3);
    }
    bits[(size_t)r * 128 + g] = m;
    return;
  }
  // ---- Wh path: 8 rows (same batch) per block ----
  __shared__ float sW[4096];
  __shared__ unsigned short T[64][8];
#pragma unroll
  for (int i = 0; i < 16; ++i) sW[i * 256 + t] = W[i * 256 + t];
  __syncthreads();
  const int wv = t >> 6, lane = t & 63;
  const float a1 = a[lane], a2 = a[64 + lane];
  const int row0 = bi * 8;
  for (int r = 0; r < 2; ++r) {
    const int row = row0 + wv * 2 + r;
    const float* hr = h + (size_t)row * 64;
    float acc = 0.f;
#pragma unroll
    for (int k = 0; k < 64; ++k) acc = fmaf(hr[k], sW[k * 64 + lane], acc);
    T[lane][wv * 2 + r] = (unsigned short)bf16s(acc);
    float r1 = acc * a1, r2 = acc * a2;
#pragma unroll
    for (int sft = 32; sft; sft >>= 1) { r1 += __shfl_xor(r1, sft); r2 += __shfl_xor(r2, sft); }
    if (lane == 0) { Wh1s[row] = r1 * SCL; Wh2s[row] = r2 * SCL; }
  }
  __syncthreads();
  const int f = t >> 2, jp4 = t & 3;
  const int bidx = row0 >> 12, n0 = row0 & 4095;
  unsigned v = *(unsigned*)&T[f][jp4 * 2];
  *(unsigned*)(WhT + (((size_t)(bidx * 64 + f)) << 12) + n0 + jp4 * 2) = v;
}

// ---------------------------------------------------------------------------
// Kernel 2: masked-softmax attention, MFMA PV, softmax-normalized h' -> bf16 ws.
// Grid 256 = 4 b x 64 i-blocks (64 i each). Block 512 thr = 8 waves:
// wave (ih = w>>2, s = w&3): ih picks 32-i half, s K-splits j into 1024-chunks.
// Lane (jp, rg) computes P[i][k] directly in B-frag layout (validated r2/r3).
// Denominator via ones-MFMA (idle matrix pipe). No LDS/barriers in main loop.
// __launch_bounds__(512,2): 256-VGPR budget so the compiler can pipeline loads.
// ---------------------------------------------------------------------------
__global__ __launch_bounds__(512, 2)
void k_gat(const unsigned* __restrict__ bits,
           const unsigned short* __restrict__ WhT,
           const float* __restrict__ Wh1s, const float* __restrict__ Wh2s,
           unsigned short* __restrict__ hprime) {
  __shared__ float hp[2][64][34];   // combine buffer [ih][f][icol], 17.4 KB
  __shared__ float ls[4][64];       // denom partials [s][i-local]

  const int t = threadIdx.x;
  const int w = t >> 6, lane = t & 63;
  const int ih = w >> 2, s = w & 3;
  const int b = blockIdx.x >> 6;
  const int i0 = (blockIdx.x & 63) * 64;
  const int jp = lane & 15;    // B-frag col (i) / A-frag row
  const int rg = lane >> 4;    // k-group

  const int iA = i0 + ih * 32 + jp;       // it = 0 row
  const int iB = iA + 16;                 // it = 1 row
  const float w1A = Wh1s[b * NN + iA];
  const float w1B = Wh1s[b * NN + iB];
  const float* __restrict__ w2base = Wh2s + b * NN;
  const unsigned* __restrict__ bq0 = bits + (size_t)iA * 128 + s * 32;
  const unsigned* __restrict__ bq1 = bits + (size_t)iB * 128 + s * 32;
  const unsigned short* __restrict__ abase =
      WhT + (((size_t)(b * 64 + jp)) << 12) + rg * 8;

  f32x4 acc[4][2];
#pragma unroll
  for (int ft = 0; ft < 4; ++ft)
#pragma unroll
    for (int it = 0; it < 2; ++it) acc[ft][it] = (f32x4){0.f, 0.f, 0.f, 0.f};
  f32x4 accd[2] = {(f32x4){0.f, 0.f, 0.f, 0.f}, (f32x4){0.f, 0.f, 0.f, 0.f}};
  bf16x8 ones;
#pragma unroll
  for (int e = 0; e < 8; ++e) ones[e] = (short)0x3F80;

  int4 mq0 = *(const int4*)bq0;
  int4 mq1 = *(const int4*)bq1;
  const int jbase = s * 1024;

  for (int u = 0; u < 8; ++u) {
    int4 nq0 = *(const int4*)(bq0 + u * 4 + 4);   // prefetch (u=7 reads 16B of
    int4 nq1 = *(const int4*)(bq1 + u * 4 + 4);   // scratch slack - unused)
    const unsigned mw0[4] = {(unsigned)mq0.x, (unsigned)mq0.y, (unsigned)mq0.z, (unsigned)mq0.w};
    const unsigned mw1[4] = {(unsigned)mq1.x, (unsigned)mq1.y, (unsigned)mq1.z, (unsigned)mq1.w};
#pragma unroll
    for (int v = 0; v < 4; ++v) {
      const int j0 = jbase + u * 128 + v * 32;
      bf16x8 af[4];
#pragma unroll
      for (int ft = 0; ft < 4; ++ft)
        af[ft] = *(const bf16x8*)(abase + (ft << 16) + j0);
      const float4 w2a = *(const float4*)(w2base + j0 + rg * 8);
      const float4 w2b = *(const float4*)(w2base + j0 + rg * 8 + 4);
      const unsigned mb0 = mw0[v] >> (rg * 8);
      const unsigned mb1 = mw1[v] >> (rg * 8);
      const float wv[8] = {w2a.x, w2a.y, w2a.z, w2a.w, w2b.x, w2b.y, w2b.z, w2b.w};
      bf16x8 p0, p1;
#pragma unroll
      for (int e = 0; e < 8; ++e) {
        float yA = w1A + wv[e];
        float tA = fmaxf(yA, 0.2f * yA);
        tA = ((mb0 >> e) & 1u) ? tA : -1e30f;
        p0[e] = bf16s(exp2_fast(tA));
        float yB = w1B + wv[e];
        float tB = fmaxf(yB, 0.2f * yB);
        tB = ((mb1 >> e) & 1u) ? tB : -1e30f;
        p1[e] = bf16s(exp2_fast(tB));
      }
      accd[0] = __builtin_amdgcn_mfma_f32_16x16x32_bf16(ones, p0, accd[0], 0, 0, 0);
      accd[1] = __builtin_amdgcn_mfma_f32_16x16x32_bf16(ones, p1, accd[1], 0, 0, 0);
#pragma unroll
      for (int ft = 0; ft < 4; ++ft) {
        acc[ft][0] = __builtin_amdgcn_mfma_f32_16x16x32_bf16(af[ft], p0, acc[ft][0], 0, 0, 0);
        acc[ft][1] = __builtin_amdgcn_mfma_f32_16x16x32_bf16(af[ft], p1, acc[ft][1], 0, 0, 0);
      }
    }
    mq0 = nq0; mq1 = nq1;
  }

  // denom partials (all lanes with same jp hold identical accd values)
  if (rg == 0) {
    ls[s][ih * 32 + jp]      = accd[0][0];
    ls[s][ih * 32 + 16 + jp] = accd[1][0];
  }
  // combine h' partials across s into hp[ih] (phase-serialized)
  if (s == 3) {
#pragma unroll
    for (int ft = 0; ft < 4; ++ft)
#pragma unroll
      for (int it = 0; it < 2; ++it)
#pragma unroll
        for (int r = 0; r < 4; ++r)
          hp[ih][ft * 16 + rg * 4 + r][it * 16 + jp] = acc[ft][it][r];
  }
  __syncthreads();
  if (s == 2) {
#pragma unroll
    for (int ft = 0; ft < 4; ++ft)
#pragma unroll
      for (int it = 0; it < 2; ++it)
#pragma unroll
        for (int r = 0; r < 4; ++r)
          hp[ih][ft * 16 + rg * 4 + r][it * 16 + jp] += acc[ft][it][r];
  }
  __syncthreads();
  if (s == 1) {
#pragma unroll
    for (int ft = 0; ft < 4; ++ft)
#pragma unroll
      for (int it = 0; it < 2; ++it)
#pragma unroll
        for (int r = 0; r < 4; ++r)
          hp[ih][ft * 16 + rg * 4 + r][it * 16 + jp] += acc[ft][it][r];
  }
  __syncthreads();
  if (s == 0) {
#pragma unroll
    for (int ft = 0; ft < 4; ++ft)
#pragma unroll
      for (int it = 0; it < 2; ++it)
#pragma unroll
        for (int r = 0; r < 4; ++r)
          hp[ih][ft * 16 + rg * 4 + r][it * 16 + jp] += acc[ft][it][r];
  }
  __syncthreads();

  // normalize + transposed store: thread -> (i-local = t>>3, f-group = t&7)
  const int il = t >> 3, fg = t & 7;
  const float ltot = ls[0][il] + ls[1][il] + ls[2][il] + ls[3][il];
  const float invl = 1.f / ltot;
  const int ihh = il >> 5, ic = il & 31;
  bf16x8 pk;
#pragma unroll
  for (int e = 0; e < 8; ++e)
    pk[e] = bf16s(hp[ihh][fg * 8 + e][ic] * invl);
  *(bf16x8*)(hprime + (((size_t)(b * NN + i0 + il)) << 6) + fg * 8) = pk;
}

// ---------------------------------------------------------------------------
// Kernel 3: BatchNorm over (b,f) per node + residual + ELU.
// Block 256 thr = 4 waves (wave = b), 8 nodes per block, grid 512.
// ---------------------------------------------------------------------------
__global__ __launch_bounds__(256)
void k_bn(const float* __restrict__ h, const unsigned short* __restrict__ hprime,
          const float* __restrict__ gamma, const float* __restrict__ beta,
          float* __restrict__ out) {
  __shared__ float bnp[8][4][2];
  const int t = threadIdx.x;
  const int w = t >> 6, lane = t & 63;   // w = batch
  const int i0 = blockIdx.x * 8;
  float x[8];
#pragma unroll
  for (int ii = 0; ii < 8; ++ii) {
    unsigned u = (unsigned)hprime[(((size_t)(w * NN + i0 + ii)) << 6) + lane] << 16;
    float xv = *(float*)&u;
    x[ii] = xv;
    float s1 = xv, s2 = xv * xv;
#pragma unroll
    for (int m = 32; m; m >>= 1) { s1 += __shfl_xor(s1, m); s2 += __shfl_xor(s2, m); }
    if (lane == 0) { bnp[ii][w][0] = s1; bnp[ii][w][1] = s2; }
  }
  __syncthreads();
#pragma unroll
  for (int ii = 0; ii < 8; ++ii) {
    const float t1 = bnp[ii][0][0] + bnp[ii][1][0] + bnp[ii][2][0] + bnp[ii][3][0];
    const float t2 = bnp[ii][0][1] + bnp[ii][1][1] + bnp[ii][2][1] + bnp[ii][3][1];
    const float mean = t1 * (1.f / 256.f);
    const float var  = t2 * (1.f / 256.f) - mean * mean;
    const float sc = gamma[i0 + ii] * rsqrtf(var + 1e-5f);
    const float bt = beta[i0 + ii];
    const size_t off = (((size_t)(w * NN + i0 + ii)) << 6) + lane;
    float o = sc * (x[ii] - mean) + bt + h[off];
    o = o > 0.f ? o : exp2_fast(o * LOG2E) - 1.f;
    out[off] = o;
  }
}

// ---------------------------------------------------------------------------
extern "C" void kernel_launch(void* const* d_in, const int* in_sizes, int n_in,
                              void* d_out, int out_size, void* d_ws, size_t ws_size,
                              hipStream_t stream) {
  (void)in_sizes; (void)n_in; (void)out_size; (void)ws_size;
  const float* h     = (const float*)d_in[0];
  const int*   adj   = (const int*)d_in[1];
  const float* W     = (const float*)d_in[2];
  const float* a     = (const float*)d_in[3];
  const float* gamma = (const float*)d_in[4];
  const float* beta  = (const float*)d_in[5];
  float* out = (float*)d_out;

  char* ws = (char*)d_ws;
  unsigned short* WhT = (unsigned short*)ws;                     // 2 MB
  float* Wh1s = (float*)(ws + 2097152);                          // 64 KB
  float* Wh2s = (float*)(ws + 2097152 + 65536);                  // 64 KB
  unsigned* bits = (unsigned*)(ws + 2228224);                    // 2 MB
  unsigned short* hprime = (unsigned short*)(ws + 4325376);      // 2 MB

  k_prep<<<4096, 256, 0, stream>>>(h, W, a, adj, WhT, Wh1s, Wh2s, bits);
  k_gat<<<256, 512, 0, stream>>>(bits, WhT, Wh1s, Wh2s, hprime);
  k_bn<<<512, 256, 0, stream>>>(h, hprime, gamma, beta, out);
}